// Round 1
// baseline (2221.736 us; speedup 1.0000x reference)
//
#include <hip/hip_runtime.h>
#include <math.h>

#define NDIM 128
#define B_GRAPHS 8192
#define IDX 16
#define EPG 32
#define NN (B_GRAPHS*IDX)      // 131072 nodes
#define NE (B_GRAPHS*EPG)      // 262144 edges

// ---------------------------------------------------------------------------
// Compose per-layer weights:
//   WgiT[l][k][r] (512 x 384, K-major/transposed) where k-segments map to
//   A' = [S_in(128) | S_out(128) | indeg*h(128) | outdeg*h(128)]:
//     k<128   : M1 = Wih @ msg_W[:, :128]
//     k<256   : M2 = Wih @ msgr_W[:, :128]
//     k<384   : M3 = Wih @ msg_W[:, 128:]
//     k<512   : M4 = Wih @ msgr_W[:, 128:]
//   WhhT[l][k][r] (128 x 384) = Whh^T
//   c34[l][0][r] = Wih @ msg_b ; c34[l][1][r] = Wih @ msgr_b
// ---------------------------------------------------------------------------
__global__ __launch_bounds__(256) void compose_kernel(
    const float* __restrict__ msg_W, const float* __restrict__ msgr_W,
    const float* __restrict__ Wih,   const float* __restrict__ Whh,
    const float* __restrict__ msg_b, const float* __restrict__ msgr_b,
    float* __restrict__ WgiT, float* __restrict__ WhhT, float* __restrict__ c34)
{
    int idx = blockIdx.x*256 + threadIdx.x;
    if (idx < 2*512*384) {
        int l = idx / (512*384); int rem = idx - l*(512*384);
        int k = rem / 384; int r = rem - k*384;
        const float* wih = Wih + l*384*256 + r*256;
        const float* M; int sc;
        if (k < 128)      { M = msg_W  + l*256*256; sc = k;       }
        else if (k < 256) { M = msgr_W + l*256*256; sc = k - 128; }
        else if (k < 384) { M = msg_W  + l*256*256; sc = k - 128; }  // 128+(k-256)
        else              { M = msgr_W + l*256*256; sc = k - 256; }  // 128+(k-384)
        float acc = 0.f;
        for (int q = 0; q < 256; q++) acc = fmaf(wih[q], M[q*256 + sc], acc);
        WgiT[l*512*384 + k*384 + r] = acc;
    } else if (idx < 2*512*384 + 2*128*384) {
        int i2 = idx - 2*512*384;
        int l = i2 / (128*384); int rem = i2 - l*(128*384);
        int k = rem / 384; int r = rem - k*384;
        WhhT[l*128*384 + k*384 + r] = Whh[l*384*128 + r*128 + k];
    } else if (idx < 2*512*384 + 2*128*384 + 2*2*384) {
        int i2 = idx - (2*512*384 + 2*128*384);
        int l = i2 / 768; int rem = i2 - l*768;
        int which = rem / 384; int r = rem - which*384;
        const float* wih = Wih + l*384*256 + r*256;
        const float* bb  = (which ? msgr_b : msg_b) + l*256;
        float acc = 0.f;
        for (int q = 0; q < 256; q++) acc = fmaf(wih[q], bb[q], acc);
        c34[l*768 + which*384 + r] = acc;
    }
}

// ---------------------------------------------------------------------------
// Per-graph neighbor sums. Edges e in [g*32,(g+1)*32) all belong to graph g
// (nodes g*16..g*16+15), so everything fits in LDS, no atomics on global.
// Writes S[v] = [S_in | S_out] (N x 256) and float indeg/outdeg.
// Handles both int32 and int64 edge_index via on-device detection.
// ---------------------------------------------------------------------------
__global__ __launch_bounds__(128) void scatter_kernel(
    const float* __restrict__ hin, const int* __restrict__ ei,
    float* __restrict__ S, float* __restrict__ indeg, float* __restrict__ outdeg)
{
    int g = blockIdx.x, t = threadIdx.x;
    __shared__ float hb[16][128];
    __shared__ float sin_[16][128];
    __shared__ float sout_[16][128];
    __shared__ int sl[32], dl[32];
    __shared__ int cin[16], cout[16];
    __shared__ int flag64;
    int base = g*IDX;
    for (int r = 0; r < 16; r++) hb[r][t] = hin[(base+r)*128 + t];
    for (int r = 0; r < 16; r++) { sin_[r][t] = 0.f; sout_[r][t] = 0.f; }
    if (t < 16) { cin[t] = 0; cout[t] = 0; }
    if (t == 0) {
        // int64 arrays have all-zero odd 32-bit words for values < 2^31;
        // genuine int32 src entries 33..63 are >=16, so never all-zero.
        int orv = 0;
        for (int i = 1; i < 64; i += 2) orv |= ei[i];
        flag64 = (orv == 0);
    }
    __syncthreads();
    if (t < 32) {
        int e = g*EPG + t;
        int sv, dv;
        if (flag64) { sv = ei[2*e]; dv = ei[2*(NE + e)]; }
        else        { sv = ei[e];   dv = ei[NE + e];     }
        sl[t] = sv - base; dl[t] = dv - base;
        atomicAdd(&cout[sl[t]], 1); atomicAdd(&cin[dl[t]], 1);
    }
    __syncthreads();
    for (int e = 0; e < 32; e++) {
        sin_[dl[e]][t]  += hb[sl[e]][t];
        sout_[sl[e]][t] += hb[dl[e]][t];
    }
    for (int r = 0; r < 16; r++) {
        int v = base + r;
        S[v*256 + t]       = sin_[r][t];
        S[v*256 + 128 + t] = sout_[r][t];
    }
    if (t < 16) { indeg[base+t] = (float)cin[t]; outdeg[base+t] = (float)cout[t]; }
}

// ---------------------------------------------------------------------------
// Fused GEMM + GRU. Block: 64 nodes x 32 output dims (grid.y covers 128/32).
// For each output dim j it accumulates the column triple {j,128+j,256+j} of
// gi (K=512 over [S | indeg*h | outdeg*h]) and gh (K=128 over h), then does
// the full GRU in the epilogue. 256 threads: tj = output col, tg*8+mi = node.
// ---------------------------------------------------------------------------
#define AS_LD 68   // 64 + pad: keeps 16B alignment, spreads banks

__global__ __launch_bounds__(256) void gemm_gru_kernel(
    const float* __restrict__ hin, const float* __restrict__ S,
    const float* __restrict__ indeg, const float* __restrict__ outdeg,
    const float* __restrict__ WgiT, const float* __restrict__ WhhT,
    const float* __restrict__ c34,
    const float* __restrict__ bih, const float* __restrict__ bhh,
    float* __restrict__ hout)
{
    const int n0 = blockIdx.x * 64;
    const int j0 = blockIdx.y * 32;
    const int tid = threadIdx.x;
    const int tj = tid & 31;
    const int tg = tid >> 5;   // 0..7

    __shared__ float As[64*AS_LD];   // [k][m]
    __shared__ float Bs[64*96];      // [k][3 segs * 32 cols]

    float acc_r[8], acc_z[8], acc_n[8], hacc_r[8], hacc_z[8], hacc_n[8];
#pragma unroll
    for (int i = 0; i < 8; i++) {
        acc_r[i]=acc_z[i]=acc_n[i]=hacc_r[i]=hacc_z[i]=hacc_n[i]=0.f;
    }

    // ---- Phase A: S part, k in [0,256) ----
    for (int kc = 0; kc < 256; kc += 64) {
#pragma unroll
        for (int i = 0; i < 16; i++) {
            int lin = tid + 256*i; int m = lin >> 6, k = lin & 63;
            As[k*AS_LD + m] = S[(n0+m)*256 + kc + k];
        }
#pragma unroll
        for (int seg = 0; seg < 3; seg++)
#pragma unroll
        for (int i = 0; i < 8; i++) {
            int lin = tid + 256*i; int kk = lin >> 5, c = lin & 31;
            Bs[kk*96 + seg*32 + c] = WgiT[(kc+kk)*384 + seg*128 + j0 + c];
        }
        __syncthreads();
#pragma unroll 4
        for (int k = 0; k < 64; k++) {
            float b0 = Bs[k*96+tj], b1 = Bs[k*96+32+tj], b2 = Bs[k*96+64+tj];
#pragma unroll
            for (int mi = 0; mi < 8; mi++) {
                float a = As[k*AS_LD + tg*8 + mi];
                acc_r[mi] = fmaf(a, b0, acc_r[mi]);
                acc_z[mi] = fmaf(a, b1, acc_z[mi]);
                acc_n[mi] = fmaf(a, b2, acc_n[mi]);
            }
        }
        __syncthreads();
    }
    // ---- Phase B: indeg*h, k in [256,384) ----
    for (int kc = 0; kc < 128; kc += 64) {
#pragma unroll
        for (int i = 0; i < 16; i++) {
            int lin = tid + 256*i; int m = lin >> 6, k = lin & 63;
            As[k*AS_LD + m] = hin[(n0+m)*128 + kc + k] * indeg[n0+m];
        }
#pragma unroll
        for (int seg = 0; seg < 3; seg++)
#pragma unroll
        for (int i = 0; i < 8; i++) {
            int lin = tid + 256*i; int kk = lin >> 5, c = lin & 31;
            Bs[kk*96 + seg*32 + c] = WgiT[(256+kc+kk)*384 + seg*128 + j0 + c];
        }
        __syncthreads();
#pragma unroll 4
        for (int k = 0; k < 64; k++) {
            float b0 = Bs[k*96+tj], b1 = Bs[k*96+32+tj], b2 = Bs[k*96+64+tj];
#pragma unroll
            for (int mi = 0; mi < 8; mi++) {
                float a = As[k*AS_LD + tg*8 + mi];
                acc_r[mi] = fmaf(a, b0, acc_r[mi]);
                acc_z[mi] = fmaf(a, b1, acc_z[mi]);
                acc_n[mi] = fmaf(a, b2, acc_n[mi]);
            }
        }
        __syncthreads();
    }
    // ---- Phase C: outdeg*h, k in [384,512) ----
    for (int kc = 0; kc < 128; kc += 64) {
#pragma unroll
        for (int i = 0; i < 16; i++) {
            int lin = tid + 256*i; int m = lin >> 6, k = lin & 63;
            As[k*AS_LD + m] = hin[(n0+m)*128 + kc + k] * outdeg[n0+m];
        }
#pragma unroll
        for (int seg = 0; seg < 3; seg++)
#pragma unroll
        for (int i = 0; i < 8; i++) {
            int lin = tid + 256*i; int kk = lin >> 5, c = lin & 31;
            Bs[kk*96 + seg*32 + c] = WgiT[(384+kc+kk)*384 + seg*128 + j0 + c];
        }
        __syncthreads();
#pragma unroll 4
        for (int k = 0; k < 64; k++) {
            float b0 = Bs[k*96+tj], b1 = Bs[k*96+32+tj], b2 = Bs[k*96+64+tj];
#pragma unroll
            for (int mi = 0; mi < 8; mi++) {
                float a = As[k*AS_LD + tg*8 + mi];
                acc_r[mi] = fmaf(a, b0, acc_r[mi]);
                acc_z[mi] = fmaf(a, b1, acc_z[mi]);
                acc_n[mi] = fmaf(a, b2, acc_n[mi]);
            }
        }
        __syncthreads();
    }
    // ---- Phase D: gh = Whh @ h ----
    for (int kc = 0; kc < 128; kc += 64) {
#pragma unroll
        for (int i = 0; i < 16; i++) {
            int lin = tid + 256*i; int m = lin >> 6, k = lin & 63;
            As[k*AS_LD + m] = hin[(n0+m)*128 + kc + k];
        }
#pragma unroll
        for (int seg = 0; seg < 3; seg++)
#pragma unroll
        for (int i = 0; i < 8; i++) {
            int lin = tid + 256*i; int kk = lin >> 5, c = lin & 31;
            Bs[kk*96 + seg*32 + c] = WhhT[(kc+kk)*384 + seg*128 + j0 + c];
        }
        __syncthreads();
#pragma unroll 4
        for (int k = 0; k < 64; k++) {
            float b0 = Bs[k*96+tj], b1 = Bs[k*96+32+tj], b2 = Bs[k*96+64+tj];
#pragma unroll
            for (int mi = 0; mi < 8; mi++) {
                float a = As[k*AS_LD + tg*8 + mi];
                hacc_r[mi] = fmaf(a, b0, hacc_r[mi]);
                hacc_z[mi] = fmaf(a, b1, hacc_z[mi]);
                hacc_n[mi] = fmaf(a, b2, hacc_n[mi]);
            }
        }
        __syncthreads();
    }

    // ---- Epilogue: GRU ----
    const float* c3 = c34;
    const float* c4 = c34 + 384;
    const int j = j0 + tj;
#pragma unroll
    for (int mi = 0; mi < 8; mi++) {
        int v = n0 + tg*8 + mi;
        float di = indeg[v], dof = outdeg[v];
        float gr = acc_r[mi] + di*c3[j]     + dof*c4[j]     + bih[j];
        float gz = acc_z[mi] + di*c3[128+j] + dof*c4[128+j] + bih[128+j];
        float gn = acc_n[mi] + di*c3[256+j] + dof*c4[256+j] + bih[256+j];
        float hr = hacc_r[mi] + bhh[j];
        float hz = hacc_z[mi] + bhh[128+j];
        float hn = hacc_n[mi] + bhh[256+j];
        float r = 1.f/(1.f + expf(-(gr + hr)));
        float z = 1.f/(1.f + expf(-(gz + hz)));
        float n = tanhf(gn + r*hn);
        float hold = hin[v*128 + j];
        hout[v*128 + j] = n + z*(hold - n);
    }
}

// ---------------------------------------------------------------------------
// Gated graph pooling. out[g][c] = fm_W[c] . (sum_r gate_r * h_r)
//                                  + fm_b[c] * (sum_r gate_r)
// Two graphs per 256-thread block.
// ---------------------------------------------------------------------------
__global__ __launch_bounds__(256) void aggr_kernel(
    const float* __restrict__ hf,
    const float* __restrict__ fm_W,  const float* __restrict__ fm_b,
    const float* __restrict__ gm_W,  const float* __restrict__ gm_b,
    const float* __restrict__ fmi_W, const float* __restrict__ fmi_b,
    const float* __restrict__ gmi_W, const float* __restrict__ gmi_b,
    float* __restrict__ out1, float* __restrict__ out2)
{
    int half = threadIdx.x >> 7;
    int t = threadIdx.x & 127;
    int g = blockIdx.x*2 + half;
    __shared__ float hb[2][16][128];
    __shared__ float hw1[2][128], hw2[2][128];
    __shared__ float gate1[2][16], gate2[2][16];
    __shared__ float sg[2][2];
    int base = g*IDX;
    for (int r = 0; r < 16; r++) hb[half][r][t] = hf[(base+r)*128 + t];
    __syncthreads();
    if (t < 16) {
        float a1 = 0.f, a2 = 0.f;
        for (int k = 0; k < 128; k++) {
            float x = hb[half][t][k];
            a1 = fmaf(gm_W[k],  x, a1);
            a2 = fmaf(gmi_W[k], x, a2);
        }
        gate1[half][t] = 1.f/(1.f + expf(-(a1 + gm_b[0])));
        gate2[half][t] = 1.f/(1.f + expf(-(a2 + gmi_b[0])));
    }
    __syncthreads();
    float w1 = 0.f, w2 = 0.f;
    for (int r = 0; r < 16; r++) {
        w1 = fmaf(gate1[half][r], hb[half][r][t], w1);
        w2 = fmaf(gate2[half][r], hb[half][r][t], w2);
    }
    hw1[half][t] = w1; hw2[half][t] = w2;
    if (t == 0) {
        float s1 = 0.f, s2 = 0.f;
        for (int r = 0; r < 16; r++) { s1 += gate1[half][r]; s2 += gate2[half][r]; }
        sg[half][0] = s1; sg[half][1] = s2;
    }
    __syncthreads();
    float acc1 = 0.f, acc2 = 0.f;
    for (int k = 0; k < 128; k++) {
        acc1 = fmaf(fm_W[t*128+k],  hw1[half][k], acc1);
        acc2 = fmaf(fmi_W[t*128+k], hw2[half][k], acc2);
    }
    out1[g*128 + t] = acc1 + fm_b[t]*sg[half][0];
    out2[g*128 + t] = acc2 + fmi_b[t]*sg[half][1];
}

// ---------------------------------------------------------------------------
extern "C" void kernel_launch(void* const* d_in, const int* in_sizes, int n_in,
                              void* d_out, int out_size, void* d_ws, size_t ws_size,
                              hipStream_t stream)
{
    const float* h     = (const float*)d_in[0];
    const int*   ei    = (const int*)d_in[1];
    const float* msgW  = (const float*)d_in[2];
    const float* msgb  = (const float*)d_in[3];
    const float* msgrW = (const float*)d_in[4];
    const float* msgrb = (const float*)d_in[5];
    const float* Wih   = (const float*)d_in[6];
    const float* Whh   = (const float*)d_in[7];
    const float* bih   = (const float*)d_in[8];
    const float* bhh   = (const float*)d_in[9];
    const float* fmW   = (const float*)d_in[10];
    const float* fmb   = (const float*)d_in[11];
    const float* gmW   = (const float*)d_in[12];
    const float* gmb   = (const float*)d_in[13];
    const float* fmiW  = (const float*)d_in[14];
    const float* fmib  = (const float*)d_in[15];
    const float* gmiW  = (const float*)d_in[16];
    const float* gmib  = (const float*)d_in[17];

    float* ws     = (float*)d_ws;
    float* S      = ws;                          // N*256
    float* hmid   = S + (size_t)NN*256;          // N*128
    float* indeg  = hmid + (size_t)NN*128;       // N
    float* outdeg = indeg + NN;                  // N
    float* WgiT   = outdeg + NN;                 // 2*512*384
    float* WhhT   = WgiT + 2*512*384;            // 2*128*384
    float* c34    = WhhT + 2*128*384;            // 2*768

    float* hf   = (float*)d_out;
    float* out1 = hf + (size_t)NN*128;
    float* out2 = out1 + (size_t)B_GRAPHS*128;

    int compose_items = 2*512*384 + 2*128*384 + 2*2*384;
    compose_kernel<<<(compose_items + 255)/256, 256, 0, stream>>>(
        msgW, msgrW, Wih, Whh, msgb, msgrb, WgiT, WhhT, c34);

    // layer 0
    scatter_kernel<<<B_GRAPHS, 128, 0, stream>>>(h, ei, S, indeg, outdeg);
    gemm_gru_kernel<<<dim3(NN/64, 4), 256, 0, stream>>>(
        h, S, indeg, outdeg, WgiT, WhhT, c34, bih, bhh, hmid);

    // layer 1
    scatter_kernel<<<B_GRAPHS, 128, 0, stream>>>(hmid, ei, S, indeg, outdeg);
    gemm_gru_kernel<<<dim3(NN/64, 4), 256, 0, stream>>>(
        hmid, S, indeg, outdeg, WgiT + 512*384, WhhT + 128*384, c34 + 768,
        bih + 384, bhh + 384, hf);

    aggr_kernel<<<B_GRAPHS/2, 256, 0, stream>>>(
        hf, fmW, fmb, gmW, gmb, fmiW, fmib, gmiW, gmib, out1, out2);
}

// Round 2
// 625.598 us; speedup vs baseline: 3.5514x; 3.5514x over previous
//
#include <hip/hip_runtime.h>
#include <math.h>
#include <stdint.h>

#define NDIM 128
#define B_GRAPHS 8192
#define IDX 16
#define EPG 32
#define NN (B_GRAPHS*IDX)      // 131072 nodes
#define NE (B_GRAPHS*EPG)      // 262144 edges

typedef short bf16x8 __attribute__((ext_vector_type(8)));
typedef float f32x4  __attribute__((ext_vector_type(4)));

__device__ inline unsigned short f2bf(float x) {
    union { float f; unsigned u; } v; v.f = x;
    unsigned r = v.u + 0x7fff + ((v.u >> 16) & 1);
    return (unsigned short)(r >> 16);
}
__device__ inline float bf2f(unsigned short b) {
    union { unsigned u; float f; } v; v.u = ((unsigned)b) << 16;
    return v.f;
}
__device__ inline float sigm(float x) { return 1.f/(1.f + __expf(-x)); }
__device__ inline float tanh_f(float x) {
    float ax = fabsf(x);
    float t  = __expf(-2.f*ax);
    float r  = (1.f - t)/(1.f + t);
    return copysignf(r, x);
}

#define GLOAD_LDS16(g, l) \
    __builtin_amdgcn_global_load_lds( \
        (const __attribute__((address_space(1))) unsigned int*)(g), \
        (__attribute__((address_space(3))) unsigned int*)(l), 16, 0, 0)

// ---------------------------------------------------------------------------
// Compose bf16 weight matrix WB[l][c][k]  (512 cols x 640 K) and c34.
// K segments: [S_in(128) | S_out(128) | indeg*h(128) | outdeg*h(128) | h(128)]
// Col segments: [r-sum(128) | z-sum(128) | gi_n(128) | gh_n(128)]
// ---------------------------------------------------------------------------
__global__ __launch_bounds__(256) void compose_kernel(
    const float* __restrict__ msg_W, const float* __restrict__ msgr_W,
    const float* __restrict__ Wih,   const float* __restrict__ Whh,
    const float* __restrict__ msg_b, const float* __restrict__ msgr_b,
    unsigned short* __restrict__ WB, float* __restrict__ c34)
{
    int idx = blockIdx.x*256 + threadIdx.x;
    const int TWB = 2*512*640;
    if (idx < TWB) {
        int l = idx / (512*640); int rem = idx - l*(512*640);
        int c = rem / 640; int k = rem - c*640;
        float val;
        if (k < 512) {
            if (c < 384) {
                const float* wih = Wih + l*384*256 + c*256;
                const float* M; int sc;
                if (k < 128)      { M = msg_W  + l*256*256; sc = k;       }
                else if (k < 256) { M = msgr_W + l*256*256; sc = k - 128; }
                else if (k < 384) { M = msg_W  + l*256*256; sc = k - 128; }
                else              { M = msgr_W + l*256*256; sc = k - 256; }
                float acc = 0.f;
                for (int q = 0; q < 256; q++) acc = fmaf(wih[q], M[q*256 + sc], acc);
                val = acc;
            } else val = 0.f;
        } else {
            int kk = k - 512;
            if (c < 256)      val = Whh[l*384*128 + c*128 + kk];
            else if (c < 384) val = 0.f;
            else              val = Whh[l*384*128 + (c-128)*128 + kk];
        }
        WB[idx] = f2bf(val);
    } else if (idx < TWB + 2*2*384) {
        int i2 = idx - TWB;
        int l = i2 / 768; int rem = i2 - l*768;
        int which = rem / 384; int r = rem - which*384;
        const float* wih = Wih + l*384*256 + r*256;
        const float* bb  = (which ? msgr_b : msg_b) + l*256;
        float acc = 0.f;
        for (int q = 0; q < 256; q++) acc = fmaf(wih[q], bb[q], acc);
        c34[l*768 + which*384 + r] = acc;
    }
}

// ---------------------------------------------------------------------------
// Init: per-graph edge decode + degree + packed edges + A0 build (bf16).
// A[v] = [S_in | S_out | indeg*h | outdeg*h | h]
// ---------------------------------------------------------------------------
__global__ __launch_bounds__(128) void init_kernel(
    const float* __restrict__ hin, const int* __restrict__ ei,
    unsigned short* __restrict__ A, float* __restrict__ indeg,
    float* __restrict__ outdeg, unsigned char* __restrict__ pack)
{
    int g = blockIdx.x, t = threadIdx.x;
    __shared__ float hb[16][128];
    __shared__ float sin_[16][128];
    __shared__ float sout_[16][128];
    __shared__ int sl[32], dl[32];
    __shared__ int cin[16], cout[16];
    __shared__ int flag64;
    int base = g*IDX;
    for (int r = 0; r < 16; r++) hb[r][t] = hin[(size_t)(base+r)*128 + t];
    for (int r = 0; r < 16; r++) { sin_[r][t] = 0.f; sout_[r][t] = 0.f; }
    if (t < 16) { cin[t] = 0; cout[t] = 0; }
    if (t == 0) {
        int orv = 0;
        for (int i = 1; i < 64; i += 2) orv |= ei[i];
        flag64 = (orv == 0);
    }
    __syncthreads();
    if (t < 32) {
        int e = g*EPG + t;
        int sv, dv;
        if (flag64) { sv = ei[2*e]; dv = ei[2*(NE + e)]; }
        else        { sv = ei[e];   dv = ei[NE + e];     }
        sl[t] = sv - base; dl[t] = dv - base;
        atomicAdd(&cout[sl[t]], 1); atomicAdd(&cin[dl[t]], 1);
        pack[g*32 + t] = (unsigned char)((sl[t] & 15) | ((dl[t] & 15) << 4));
    }
    __syncthreads();
    for (int e = 0; e < 32; e++) {
        sin_[dl[e]][t]  += hb[sl[e]][t];
        sout_[sl[e]][t] += hb[dl[e]][t];
    }
    for (int r = 0; r < 16; r++) {
        size_t v = base + r;
        float di = (float)cin[r], dof = (float)cout[r];
        A[v*640 + t]        = f2bf(sin_[r][t]);
        A[v*640 + 128 + t]  = f2bf(sout_[r][t]);
        A[v*640 + 256 + t]  = f2bf(di  * hb[r][t]);
        A[v*640 + 384 + t]  = f2bf(dof * hb[r][t]);
        A[v*640 + 512 + t]  = f2bf(hb[r][t]);
    }
    if (t < 16) { indeg[base+t] = (float)cin[t]; outdeg[base+t] = (float)cout[t]; }
}

// ---------------------------------------------------------------------------
// MFMA GEMM: G[rows x 512] = A[rows x 640] @ WB^T  (per-col-block K ranges).
// 128x128 tile per block, 4 waves (2x2), 16x16x32 bf16 MFMA.
// LDS XOR-swizzle (slot ^= row&7) with pre-swizzled global_load_lds source.
// ---------------------------------------------------------------------------
__global__ __launch_bounds__(256) void gemm_kernel(
    const unsigned short* __restrict__ A,
    const unsigned short* __restrict__ WB,
    unsigned short* __restrict__ G, int chunk0)
{
    const int n0 = chunk0 + blockIdx.x*128;
    const int jb = blockIdx.y;
    int k0, ksteps;
    if (jb < 2)       { k0 = 0;   ksteps = 10; }
    else if (jb == 2) { k0 = 0;   ksteps = 8;  }
    else              { k0 = 512; ksteps = 2;  }

    __shared__ unsigned short As[128*64];
    __shared__ unsigned short Bs[128*64];

    const int tid  = threadIdx.x;
    const int lane = tid & 63;
    const int wid  = tid >> 6;          // 0..3
    const int wr   = wid >> 1, wc = wid & 1;
    const int l15  = lane & 15, l4 = lane >> 4;
    const int sxor = l15 & 7;

    f32x4 acc[4][4] = {};

    for (int ks = 0; ks < ksteps; ks++) {
        int kc = k0 + ks*64;
#pragma unroll
        for (int i = 0; i < 4; i++) {
            int u = i*256 + tid;
            int row = u >> 3, s = u & 7;
            int slot = s ^ (row & 7);
            GLOAD_LDS16(A  + (size_t)(n0 + row)*640    + kc + slot*8,
                        (char*)As + (size_t)u*16);
            GLOAD_LDS16(WB + (size_t)(jb*128 + row)*640 + kc + slot*8,
                        (char*)Bs + (size_t)u*16);
        }
        __syncthreads();
#pragma unroll
        for (int kk = 0; kk < 2; kk++) {
            bf16x8 af[4], bfr[4];
            int slot = (kk*4 + l4) ^ sxor;
#pragma unroll
            for (int x = 0; x < 4; x++) {
                int arow = wr*64 + x*16 + l15;
                af[x]  = *(const bf16x8*)((const char*)As + arow*128 + slot*16);
                int bcol = wc*64 + x*16 + l15;
                bfr[x] = *(const bf16x8*)((const char*)Bs + bcol*128 + slot*16);
            }
#pragma unroll
            for (int mi = 0; mi < 4; mi++)
#pragma unroll
                for (int ni = 0; ni < 4; ni++)
                    acc[mi][ni] = __builtin_amdgcn_mfma_f32_16x16x32_bf16(
                        af[mi], bfr[ni], acc[mi][ni], 0, 0, 0);
        }
        __syncthreads();
    }

#pragma unroll
    for (int mi = 0; mi < 4; mi++) {
        int row = (n0 - chunk0) + wr*64 + mi*16 + l4*4;
#pragma unroll
        for (int ni = 0; ni < 4; ni++) {
            int col = jb*128 + wc*64 + ni*16 + l15;
#pragma unroll
            for (int q = 0; q < 4; q++)
                G[(size_t)(row + q)*512 + col] = f2bf(acc[mi][ni][q]);
        }
    }
}

// ---------------------------------------------------------------------------
// Fused GRU epilogue + scatter for next layer (writes A in place, own rows
// only). FINAL=true writes fp32 hf instead.
// ---------------------------------------------------------------------------
template <bool FINAL>
__global__ __launch_bounds__(128) void gru_kernel(
    const unsigned short* __restrict__ G, int chunk0,
    unsigned short* __restrict__ A,
    const float* __restrict__ indeg, const float* __restrict__ outdeg,
    const unsigned char* __restrict__ pack,
    const float* __restrict__ c34l,
    const float* __restrict__ bihl, const float* __restrict__ bhhl,
    float* __restrict__ hf)
{
    const int gl = blockIdx.x;
    const int base = chunk0 + gl*IDX;
    const int g = base / IDX;
    const int t = threadIdx.x;

    __shared__ float hnew[16][128];
    __shared__ float sin_[16][128];
    __shared__ float sout_[16][128];
    __shared__ unsigned char pk[32];

    const float* c3 = c34l;
    const float* c4 = c34l + 384;
    float c3r = c3[t], c3z = c3[128+t], c3n = c3[256+t];
    float c4r = c4[t], c4z = c4[128+t], c4n = c4[256+t];
    float br  = bihl[t]     + bhhl[t];
    float bz  = bihl[128+t] + bhhl[128+t];
    float bin_ = bihl[256+t];
    float bhn  = bhhl[256+t];

    if (!FINAL) {
        if (t < 32) pk[t] = pack[g*32 + t];
        for (int r = 0; r < 16; r++) { sin_[r][t] = 0.f; sout_[r][t] = 0.f; }
    }

    for (int r = 0; r < 16; r++) {
        size_t v = base + r;
        size_t gr0 = (size_t)(v - chunk0)*512;
        float Gr  = bf2f(G[gr0 + t]);
        float Gz  = bf2f(G[gr0 + 128 + t]);
        float Gin = bf2f(G[gr0 + 256 + t]);
        float Ghn = bf2f(G[gr0 + 384 + t]);
        float hold = bf2f(A[v*640 + 512 + t]);
        float di = indeg[v], dof = outdeg[v];
        float rr = sigm(Gr + di*c3r + dof*c4r + br);
        float zz = sigm(Gz + di*c3z + dof*c4z + bz);
        float nn = tanh_f(Gin + di*c3n + dof*c4n + bin_ + rr*(Ghn + bhn));
        float hv = nn + zz*(hold - nn);
        if (FINAL) hf[v*128 + t] = hv;
        else       hnew[r][t] = hv;
    }

    if (!FINAL) {
        __syncthreads();   // pk visibility (hnew/sin/sout are column-private)
        for (int e = 0; e < 32; e++) {
            int p = pk[e];
            int s = p & 15, d = p >> 4;
            sin_[d][t]  += hnew[s][t];
            sout_[s][t] += hnew[d][t];
        }
        for (int r = 0; r < 16; r++) {
            size_t v = base + r;
            float di = indeg[v], dof = outdeg[v];
            A[v*640 + t]       = f2bf(sin_[r][t]);
            A[v*640 + 128 + t] = f2bf(sout_[r][t]);
            A[v*640 + 256 + t] = f2bf(di  * hnew[r][t]);
            A[v*640 + 384 + t] = f2bf(dof * hnew[r][t]);
            A[v*640 + 512 + t] = f2bf(hnew[r][t]);
        }
    }
}

// ---------------------------------------------------------------------------
// Gated graph pooling (unchanged from round 1).
// ---------------------------------------------------------------------------
__global__ __launch_bounds__(256) void aggr_kernel(
    const float* __restrict__ hf,
    const float* __restrict__ fm_W,  const float* __restrict__ fm_b,
    const float* __restrict__ gm_W,  const float* __restrict__ gm_b,
    const float* __restrict__ fmi_W, const float* __restrict__ fmi_b,
    const float* __restrict__ gmi_W, const float* __restrict__ gmi_b,
    float* __restrict__ out1, float* __restrict__ out2)
{
    int half = threadIdx.x >> 7;
    int t = threadIdx.x & 127;
    int g = blockIdx.x*2 + half;
    __shared__ float hb[2][16][128];
    __shared__ float hw1[2][128], hw2[2][128];
    __shared__ float gate1[2][16], gate2[2][16];
    __shared__ float sg[2][2];
    int base = g*IDX;
    for (int r = 0; r < 16; r++) hb[half][r][t] = hf[(size_t)(base+r)*128 + t];
    __syncthreads();
    if (t < 16) {
        float a1 = 0.f, a2 = 0.f;
        for (int k = 0; k < 128; k++) {
            float x = hb[half][t][k];
            a1 = fmaf(gm_W[k],  x, a1);
            a2 = fmaf(gmi_W[k], x, a2);
        }
        gate1[half][t] = 1.f/(1.f + expf(-(a1 + gm_b[0])));
        gate2[half][t] = 1.f/(1.f + expf(-(a2 + gmi_b[0])));
    }
    __syncthreads();
    float w1 = 0.f, w2 = 0.f;
    for (int r = 0; r < 16; r++) {
        w1 = fmaf(gate1[half][r], hb[half][r][t], w1);
        w2 = fmaf(gate2[half][r], hb[half][r][t], w2);
    }
    hw1[half][t] = w1; hw2[half][t] = w2;
    if (t == 0) {
        float s1 = 0.f, s2 = 0.f;
        for (int r = 0; r < 16; r++) { s1 += gate1[half][r]; s2 += gate2[half][r]; }
        sg[half][0] = s1; sg[half][1] = s2;
    }
    __syncthreads();
    float acc1 = 0.f, acc2 = 0.f;
    for (int k = 0; k < 128; k++) {
        acc1 = fmaf(fm_W[t*128+k],  hw1[half][k], acc1);
        acc2 = fmaf(fmi_W[t*128+k], hw2[half][k], acc2);
    }
    out1[g*128 + t] = acc1 + fm_b[t]*sg[half][0];
    out2[g*128 + t] = acc2 + fmi_b[t]*sg[half][1];
}

// ---------------------------------------------------------------------------
extern "C" void kernel_launch(void* const* d_in, const int* in_sizes, int n_in,
                              void* d_out, int out_size, void* d_ws, size_t ws_size,
                              hipStream_t stream)
{
    const float* h     = (const float*)d_in[0];
    const int*   ei    = (const int*)d_in[1];
    const float* msgW  = (const float*)d_in[2];
    const float* msgb  = (const float*)d_in[3];
    const float* msgrW = (const float*)d_in[4];
    const float* msgrb = (const float*)d_in[5];
    const float* Wih   = (const float*)d_in[6];
    const float* Whh   = (const float*)d_in[7];
    const float* bih   = (const float*)d_in[8];
    const float* bhh   = (const float*)d_in[9];
    const float* fmW   = (const float*)d_in[10];
    const float* fmb   = (const float*)d_in[11];
    const float* gmW   = (const float*)d_in[12];
    const float* gmb   = (const float*)d_in[13];
    const float* fmiW  = (const float*)d_in[14];
    const float* fmib  = (const float*)d_in[15];
    const float* gmiW  = (const float*)d_in[16];
    const float* gmib  = (const float*)d_in[17];

    char* w = (char*)d_ws;
    unsigned short* A    = (unsigned short*)w;  w += (size_t)NN*640*2;     // 167.8 MB
    unsigned short* WB   = (unsigned short*)w;  w += (size_t)2*512*640*2;  // 1.3 MB
    float* c34   = (float*)w;                   w += (size_t)2*768*4;
    float* indeg = (float*)w;                   w += (size_t)NN*4;
    float* outdeg= (float*)w;                   w += (size_t)NN*4;
    unsigned char* pack = (unsigned char*)w;    w += (size_t)B_GRAPHS*32;
    uintptr_t wp = ((uintptr_t)w + 15) & ~(uintptr_t)15;
    unsigned short* G = (unsigned short*)wp;
    size_t used  = wp - (uintptr_t)d_ws;
    size_t avail = ws_size > used ? ws_size - used : 0;
    long long grows = (long long)(avail / 1024);   // 512 cols * 2B per row
    grows = (grows / 128) * 128;
    if (grows > NN) grows = NN;
    if (grows < 128) grows = 128;   // ws known >= 206MB, never hit

    float* hf   = (float*)d_out;
    float* out1 = hf + (size_t)NN*128;
    float* out2 = out1 + (size_t)B_GRAPHS*128;

    int compose_items = 2*512*640 + 2*2*384;
    compose_kernel<<<(compose_items + 255)/256, 256, 0, stream>>>(
        msgW, msgrW, Wih, Whh, msgb, msgrb, WB, c34);

    init_kernel<<<B_GRAPHS, 128, 0, stream>>>(h, ei, A, indeg, outdeg, pack);

    for (int l = 0; l < 2; l++) {
        const unsigned short* WBl = WB + (size_t)l*512*640;
        const float* c34l = c34 + l*768;
        const float* bihl = bih + l*384;
        const float* bhhl = bhh + l*384;
        for (long long r0 = 0; r0 < NN; r0 += grows) {
            long long rc = NN - r0; if (rc > grows) rc = grows;
            gemm_kernel<<<dim3((unsigned)(rc/128), 4), 256, 0, stream>>>(
                A, WBl, G, (int)r0);
            if (l == 0)
                gru_kernel<false><<<(unsigned)(rc/16), 128, 0, stream>>>(
                    G, (int)r0, A, indeg, outdeg, pack, c34l, bihl, bhhl, nullptr);
            else
                gru_kernel<true><<<(unsigned)(rc/16), 128, 0, stream>>>(
                    G, (int)r0, A, indeg, outdeg, pack, c34l, bihl, bhhl, hf);
        }
    }

    aggr_kernel<<<B_GRAPHS/2, 256, 0, stream>>>(
        hf, fmW, fmb, gmW, gmb, fmiW, fmib, gmiW, gmib, out1, out2);
}

// Round 3
// 567.827 us; speedup vs baseline: 3.9127x; 1.1017x over previous
//
#include <hip/hip_runtime.h>
#include <math.h>
#include <stdint.h>

#define NDIM 128
#define B_GRAPHS 8192
#define IDX 16
#define EPG 32
#define NN (B_GRAPHS*IDX)      // 131072 nodes
#define NE (B_GRAPHS*EPG)      // 262144 edges

typedef short bf16x8 __attribute__((ext_vector_type(8)));
typedef float f32x4  __attribute__((ext_vector_type(4)));

__device__ inline unsigned short f2bf(float x) {
    union { float f; unsigned u; } v; v.f = x;
    unsigned r = v.u + 0x7fff + ((v.u >> 16) & 1);
    return (unsigned short)(r >> 16);
}
__device__ inline float bf2f(unsigned short b) {
    union { unsigned u; float f; } v; v.u = ((unsigned)b) << 16;
    return v.f;
}
__device__ inline float sigm(float x) { return 1.f/(1.f + __expf(-x)); }
__device__ inline float tanh_f(float x) {
    float ax = fabsf(x);
    float t  = __expf(-2.f*ax);
    float r  = (1.f - t)/(1.f + t);
    return copysignf(r, x);
}

#define GLOAD_LDS16(g, l) \
    __builtin_amdgcn_global_load_lds( \
        (const __attribute__((address_space(1))) unsigned int*)(g), \
        (__attribute__((address_space(3))) unsigned int*)(l), 16, 0, 0)

// ---------------------------------------------------------------------------
// Compose bf16 weight matrix WB[l][c][k]  (512 cols x 640 K) and c34.
// K segments: [S_in(128) | S_out(128) | indeg*h(128) | outdeg*h(128) | h(128)]
// Col segments: [r-sum(128) | z-sum(128) | gi_n(128) | gh_n(128)]
// ---------------------------------------------------------------------------
__global__ __launch_bounds__(256) void compose_kernel(
    const float* __restrict__ msg_W, const float* __restrict__ msgr_W,
    const float* __restrict__ Wih,   const float* __restrict__ Whh,
    const float* __restrict__ msg_b, const float* __restrict__ msgr_b,
    unsigned short* __restrict__ WB, float* __restrict__ c34)
{
    int idx = blockIdx.x*256 + threadIdx.x;
    const int TWB = 2*512*640;
    if (idx < TWB) {
        int l = idx / (512*640); int rem = idx - l*(512*640);
        int c = rem / 640; int k = rem - c*640;
        float val;
        if (k < 512) {
            if (c < 384) {
                const float* wih = Wih + l*384*256 + c*256;
                const float* M; int sc;
                if (k < 128)      { M = msg_W  + l*256*256; sc = k;       }
                else if (k < 256) { M = msgr_W + l*256*256; sc = k - 128; }
                else if (k < 384) { M = msg_W  + l*256*256; sc = k - 128; }
                else              { M = msgr_W + l*256*256; sc = k - 256; }
                float acc = 0.f;
                for (int q = 0; q < 256; q++) acc = fmaf(wih[q], M[q*256 + sc], acc);
                val = acc;
            } else val = 0.f;
        } else {
            int kk = k - 512;
            if (c < 256)      val = Whh[l*384*128 + c*128 + kk];
            else if (c < 384) val = 0.f;
            else              val = Whh[l*384*128 + (c-128)*128 + kk];
        }
        WB[idx] = f2bf(val);
    } else if (idx < TWB + 2*2*384) {
        int i2 = idx - TWB;
        int l = i2 / 768; int rem = i2 - l*768;
        int which = rem / 384; int r = rem - which*384;
        const float* wih = Wih + l*384*256 + r*256;
        const float* bb  = (which ? msgr_b : msg_b) + l*256;
        float acc = 0.f;
        for (int q = 0; q < 256; q++) acc = fmaf(wih[q], bb[q], acc);
        c34[l*768 + which*384 + r] = acc;
    }
}

// ---------------------------------------------------------------------------
// Init: per-graph edge decode + degree + packed edges + A0 build (bf16).
// A[v] = [S_in | S_out | indeg*h | outdeg*h | h]
// ---------------------------------------------------------------------------
__global__ __launch_bounds__(128) void init_kernel(
    const float* __restrict__ hin, const int* __restrict__ ei,
    unsigned short* __restrict__ A, float* __restrict__ indeg,
    float* __restrict__ outdeg, unsigned char* __restrict__ pack)
{
    int g = blockIdx.x, t = threadIdx.x;
    __shared__ float hb[16][128];
    __shared__ float sin_[16][128];
    __shared__ float sout_[16][128];
    __shared__ int sl[32], dl[32];
    __shared__ int cin[16], cout[16];
    __shared__ int flag64;
    int base = g*IDX;
    for (int r = 0; r < 16; r++) hb[r][t] = hin[(size_t)(base+r)*128 + t];
    for (int r = 0; r < 16; r++) { sin_[r][t] = 0.f; sout_[r][t] = 0.f; }
    if (t < 16) { cin[t] = 0; cout[t] = 0; }
    if (t == 0) {
        int orv = 0;
        for (int i = 1; i < 64; i += 2) orv |= ei[i];
        flag64 = (orv == 0);
    }
    __syncthreads();
    if (t < 32) {
        int e = g*EPG + t;
        int sv, dv;
        if (flag64) { sv = ei[2*e]; dv = ei[2*(NE + e)]; }
        else        { sv = ei[e];   dv = ei[NE + e];     }
        sl[t] = sv - base; dl[t] = dv - base;
        atomicAdd(&cout[sl[t]], 1); atomicAdd(&cin[dl[t]], 1);
        pack[g*32 + t] = (unsigned char)((sl[t] & 15) | ((dl[t] & 15) << 4));
    }
    __syncthreads();
    for (int e = 0; e < 32; e++) {
        sin_[dl[e]][t]  += hb[sl[e]][t];
        sout_[sl[e]][t] += hb[dl[e]][t];
    }
    for (int r = 0; r < 16; r++) {
        size_t v = base + r;
        float di = (float)cin[r], dof = (float)cout[r];
        A[v*640 + t]        = f2bf(sin_[r][t]);
        A[v*640 + 128 + t]  = f2bf(sout_[r][t]);
        A[v*640 + 256 + t]  = f2bf(di  * hb[r][t]);
        A[v*640 + 384 + t]  = f2bf(dof * hb[r][t]);
        A[v*640 + 512 + t]  = f2bf(hb[r][t]);
    }
    if (t < 16) { indeg[base+t] = (float)cin[t]; outdeg[base+t] = (float)cout[t]; }
}

// ---------------------------------------------------------------------------
// MFMA GEMM: G[rows x 512] = A[rows x 640] @ WB^T.
// 128x256 tile per block, 8 waves (2x4), 16x16x32 bf16 MFMA.
// grid.y: cb=0 -> cols 0-255 (K=640); cb=1 -> cols 256-511 with per-wave
// K-range gating (cols 256-383: ks<8; cols 384-511: ks>=8). WB zeros make
// gating a pure perf optimization.
// LDS XOR-swizzle (slot ^= row&7) with pre-swizzled global_load_lds source.
// ---------------------------------------------------------------------------
__global__ __launch_bounds__(512) void gemm_kernel(
    const unsigned short* __restrict__ A,
    const unsigned short* __restrict__ WB,
    unsigned short* __restrict__ G, int chunk0)
{
    const int n0 = chunk0 + blockIdx.x*128;
    const int cb = blockIdx.y;

    __shared__ unsigned short As[128*64];
    __shared__ unsigned short Bs[256*64];

    const int tid  = threadIdx.x;
    const int lane = tid & 63;
    const int wid  = tid >> 6;          // 0..7
    const int wr   = wid >> 2, wc = wid & 3;
    const int l15  = lane & 15, l4 = lane >> 4;
    const int sxor = l15 & 7;

    int ks_lo = 0, ks_hi = 10;
    if (cb == 1) { if (wc < 2) ks_hi = 8; else ks_lo = 8; }

    f32x4 acc[4][4] = {};

    for (int ks = 0; ks < 10; ks++) {
        int kc = ks*64;
#pragma unroll
        for (int i = 0; i < 2; i++) {      // A tile: 128x64
            int u = i*512 + tid;
            int row = u >> 3, s = u & 7;
            int slot = s ^ (row & 7);
            GLOAD_LDS16(A + (size_t)(n0 + row)*640 + kc + slot*8,
                        (char*)As + (size_t)u*16);
        }
#pragma unroll
        for (int i = 0; i < 4; i++) {      // B tile: 256x64
            int u = i*512 + tid;
            int row = u >> 3, s = u & 7;
            int slot = s ^ (row & 7);
            GLOAD_LDS16(WB + (size_t)(cb*256 + row)*640 + kc + slot*8,
                        (char*)Bs + (size_t)u*16);
        }
        __syncthreads();
        if (ks >= ks_lo && ks < ks_hi) {
#pragma unroll
            for (int kk = 0; kk < 2; kk++) {
                bf16x8 af[4], bfr[4];
                int slot = (kk*4 + l4) ^ sxor;
#pragma unroll
                for (int x = 0; x < 4; x++) {
                    int arow = wr*64 + x*16 + l15;
                    af[x]  = *(const bf16x8*)((const char*)As + arow*128 + slot*16);
                    int bcol = wc*64 + x*16 + l15;
                    bfr[x] = *(const bf16x8*)((const char*)Bs + bcol*128 + slot*16);
                }
#pragma unroll
                for (int mi = 0; mi < 4; mi++)
#pragma unroll
                    for (int ni = 0; ni < 4; ni++)
                        acc[mi][ni] = __builtin_amdgcn_mfma_f32_16x16x32_bf16(
                            af[mi], bfr[ni], acc[mi][ni], 0, 0, 0);
            }
        }
        __syncthreads();
    }

#pragma unroll
    for (int mi = 0; mi < 4; mi++) {
        int row = (n0 - chunk0) + wr*64 + mi*16 + l4*4;
#pragma unroll
        for (int ni = 0; ni < 4; ni++) {
            int col = cb*256 + wc*64 + ni*16 + l15;
#pragma unroll
            for (int q = 0; q < 4; q++)
                G[(size_t)(row + q)*512 + col] = f2bf(acc[mi][ni][q]);
        }
    }
}

// ---------------------------------------------------------------------------
// Fused GRU epilogue + scatter for next layer (writes A in place, own rows
// only). FINAL=true writes fp32 hf instead.
// ---------------------------------------------------------------------------
template <bool FINAL>
__global__ __launch_bounds__(128) void gru_kernel(
    const unsigned short* __restrict__ G, int chunk0,
    unsigned short* __restrict__ A,
    const float* __restrict__ indeg, const float* __restrict__ outdeg,
    const unsigned char* __restrict__ pack,
    const float* __restrict__ c34l,
    const float* __restrict__ bihl, const float* __restrict__ bhhl,
    float* __restrict__ hf)
{
    const int gl = blockIdx.x;
    const int base = chunk0 + gl*IDX;
    const int g = base / IDX;
    const int t = threadIdx.x;

    __shared__ float hnew[16][128];
    __shared__ float sin_[16][128];
    __shared__ float sout_[16][128];
    __shared__ unsigned char pk[32];

    const float* c3 = c34l;
    const float* c4 = c34l + 384;
    float c3r = c3[t], c3z = c3[128+t], c3n = c3[256+t];
    float c4r = c4[t], c4z = c4[128+t], c4n = c4[256+t];
    float br  = bihl[t]     + bhhl[t];
    float bz  = bihl[128+t] + bhhl[128+t];
    float bin_ = bihl[256+t];
    float bhn  = bhhl[256+t];

    if (!FINAL) {
        if (t < 32) pk[t] = pack[g*32 + t];
        for (int r = 0; r < 16; r++) { sin_[r][t] = 0.f; sout_[r][t] = 0.f; }
    }

    for (int r = 0; r < 16; r++) {
        size_t v = base + r;
        size_t gr0 = (size_t)(v - chunk0)*512;
        float Gr  = bf2f(G[gr0 + t]);
        float Gz  = bf2f(G[gr0 + 128 + t]);
        float Gin = bf2f(G[gr0 + 256 + t]);
        float Ghn = bf2f(G[gr0 + 384 + t]);
        float hold = bf2f(A[v*640 + 512 + t]);
        float di = indeg[v], dof = outdeg[v];
        float rr = sigm(Gr + di*c3r + dof*c4r + br);
        float zz = sigm(Gz + di*c3z + dof*c4z + bz);
        float nn = tanh_f(Gin + di*c3n + dof*c4n + bin_ + rr*(Ghn + bhn));
        float hv = nn + zz*(hold - nn);
        if (FINAL) hf[v*128 + t] = hv;
        else       hnew[r][t] = hv;
    }

    if (!FINAL) {
        __syncthreads();   // pk visibility (hnew/sin/sout are column-private)
        for (int e = 0; e < 32; e++) {
            int p = pk[e];
            int s = p & 15, d = p >> 4;
            sin_[d][t]  += hnew[s][t];
            sout_[s][t] += hnew[d][t];
        }
        for (int r = 0; r < 16; r++) {
            size_t v = base + r;
            float di = indeg[v], dof = outdeg[v];
            A[v*640 + t]       = f2bf(sin_[r][t]);
            A[v*640 + 128 + t] = f2bf(sout_[r][t]);
            A[v*640 + 256 + t] = f2bf(di  * hnew[r][t]);
            A[v*640 + 384 + t] = f2bf(dof * hnew[r][t]);
            A[v*640 + 512 + t] = f2bf(hnew[r][t]);
        }
    }
}

// ---------------------------------------------------------------------------
// Pool: per-node gates (all threads active, float4 dots) + gated sums.
// Block = 16 graphs (256 nodes). Outputs P1,P2 [B x 128] fp32 and sg [B][2].
// ---------------------------------------------------------------------------
__global__ __launch_bounds__(256) void pool_kernel(
    const float* __restrict__ hf,
    const float* __restrict__ gm_W,  const float* __restrict__ gm_b,
    const float* __restrict__ gmi_W, const float* __restrict__ gmi_b,
    float* __restrict__ P1, float* __restrict__ P2, float* __restrict__ sg)
{
    const int t = threadIdx.x;
    const int nbase = blockIdx.x * 256;
    __shared__ float g1s[256], g2s[256];

    {   // phase 1: one node per thread
        const float4* hp = (const float4*)(hf + (size_t)(nbase + t)*128);
        float a1 = 0.f, a2 = 0.f;
#pragma unroll
        for (int k = 0; k < 32; k++) {
            float4 hv = hp[k];
            float4 w1 = ((const float4*)gm_W)[k];
            float4 w2 = ((const float4*)gmi_W)[k];
            a1 = fmaf(hv.x,w1.x,fmaf(hv.y,w1.y,fmaf(hv.z,w1.z,fmaf(hv.w,w1.w,a1))));
            a2 = fmaf(hv.x,w2.x,fmaf(hv.y,w2.y,fmaf(hv.z,w2.z,fmaf(hv.w,w2.w,a2))));
        }
        g1s[t] = sigm(a1 + gm_b[0]);
        g2s[t] = sigm(a2 + gmi_b[0]);
    }
    __syncthreads();

    // phase 2: gated sums, coalesced over channels
    int c  = t & 127;
    int gh = t >> 7;
#pragma unroll
    for (int i = 0; i < 8; i++) {
        int glc = gh*8 + i;
        float p1 = 0.f, p2 = 0.f;
#pragma unroll
        for (int r = 0; r < 16; r++) {
            float x = hf[(size_t)(nbase + glc*16 + r)*128 + c];
            p1 = fmaf(g1s[glc*16+r], x, p1);
            p2 = fmaf(g2s[glc*16+r], x, p2);
        }
        size_t g = nbase/16 + glc;
        P1[g*128 + c] = p1;
        P2[g*128 + c] = p2;
    }
    if (t < 32) {
        int glc = t >> 1, which = t & 1;
        const float* gs = which ? g2s : g1s;
        float s = 0.f;
        for (int r = 0; r < 16; r++) s += gs[glc*16+r];
        sg[(nbase/16 + glc)*2 + which] = s;
    }
}

// ---------------------------------------------------------------------------
// Out projection: out[g][c] = fm_W[c].P[g] + fm_b[c]*sg[g]. 32 graphs/block,
// LDS-tiled fp32 microkernel, both heads sequentially.
// ---------------------------------------------------------------------------
__global__ __launch_bounds__(256) void outgemm_kernel(
    const float* __restrict__ P1, const float* __restrict__ P2,
    const float* __restrict__ sg,
    const float* __restrict__ fm_W,  const float* __restrict__ fm_b,
    const float* __restrict__ fmi_W, const float* __restrict__ fmi_b,
    float* __restrict__ out1, float* __restrict__ out2)
{
    const int g0 = blockIdx.x * 32;
    const int t  = threadIdx.x;
    __shared__ float Ws[128][33];
    __shared__ float Ps[32][33];
    const int tc = t & 15, tg = t >> 4;   // cols tc*8..+8, graphs g0+tg*2..+2

    for (int pass = 0; pass < 2; pass++) {
        const float* P  = pass ? P2 : P1;
        const float* W  = pass ? fmi_W : fm_W;
        const float* bb = pass ? fmi_b : fm_b;
        float acc[2][8] = {};
        for (int kc = 0; kc < 128; kc += 32) {
#pragma unroll
            for (int i = 0; i < 16; i++) {
                int u = i*256 + t; int r = u >> 5, k = u & 31;
                Ws[r][k] = W[(size_t)r*128 + kc + k];
            }
#pragma unroll
            for (int i = 0; i < 4; i++) {
                int u = i*256 + t; int r = u >> 5, k = u & 31;
                Ps[r][k] = P[(size_t)(g0 + r)*128 + kc + k];
            }
            __syncthreads();
#pragma unroll 8
            for (int k = 0; k < 32; k++) {
                float p0 = Ps[tg*2][k], p1v = Ps[tg*2+1][k];
#pragma unroll
                for (int j = 0; j < 8; j++) {
                    float w = Ws[tc*8+j][k];
                    acc[0][j] = fmaf(p0,  w, acc[0][j]);
                    acc[1][j] = fmaf(p1v, w, acc[1][j]);
                }
            }
            __syncthreads();
        }
        float* outp = pass ? out2 : out1;
#pragma unroll
        for (int i = 0; i < 2; i++) {
            int g = g0 + tg*2 + i;
            float sgv = sg[g*2 + pass];
#pragma unroll
            for (int j = 0; j < 8; j++) {
                int c = tc*8 + j;
                outp[(size_t)g*128 + c] = acc[i][j] + bb[c]*sgv;
            }
        }
    }
}

// ---------------------------------------------------------------------------
extern "C" void kernel_launch(void* const* d_in, const int* in_sizes, int n_in,
                              void* d_out, int out_size, void* d_ws, size_t ws_size,
                              hipStream_t stream)
{
    const float* h     = (const float*)d_in[0];
    const int*   ei    = (const int*)d_in[1];
    const float* msgW  = (const float*)d_in[2];
    const float* msgb  = (const float*)d_in[3];
    const float* msgrW = (const float*)d_in[4];
    const float* msgrb = (const float*)d_in[5];
    const float* Wih   = (const float*)d_in[6];
    const float* Whh   = (const float*)d_in[7];
    const float* bih   = (const float*)d_in[8];
    const float* bhh   = (const float*)d_in[9];
    const float* fmW   = (const float*)d_in[10];
    const float* fmb   = (const float*)d_in[11];
    const float* gmW   = (const float*)d_in[12];
    const float* gmb   = (const float*)d_in[13];
    const float* fmiW  = (const float*)d_in[14];
    const float* fmib  = (const float*)d_in[15];
    const float* gmiW  = (const float*)d_in[16];
    const float* gmib  = (const float*)d_in[17];

    char* w = (char*)d_ws;
    unsigned short* A    = (unsigned short*)w;  w += (size_t)NN*640*2;     // 167.8 MB
    unsigned short* WB   = (unsigned short*)w;  w += (size_t)2*512*640*2;  // 1.3 MB
    float* c34   = (float*)w;                   w += (size_t)2*768*4;
    float* indeg = (float*)w;                   w += (size_t)NN*4;
    float* outdeg= (float*)w;                   w += (size_t)NN*4;
    unsigned char* pack = (unsigned char*)w;    w += (size_t)B_GRAPHS*32;
    float* P1    = (float*)w;                   w += (size_t)B_GRAPHS*128*4;
    float* P2    = (float*)w;                   w += (size_t)B_GRAPHS*128*4;
    float* sgb   = (float*)w;                   w += (size_t)B_GRAPHS*2*4;
    uintptr_t wp = ((uintptr_t)w + 15) & ~(uintptr_t)15;
    unsigned short* G = (unsigned short*)wp;
    size_t used  = wp - (uintptr_t)d_ws;
    size_t avail = ws_size > used ? ws_size - used : 0;
    long long grows = (long long)(avail / 1024);   // 512 cols * 2B per row
    grows = (grows / 128) * 128;
    if (grows > NN) grows = NN;
    if (grows < 128) grows = 128;

    float* hf   = (float*)d_out;
    float* out1 = hf + (size_t)NN*128;
    float* out2 = out1 + (size_t)B_GRAPHS*128;

    int compose_items = 2*512*640 + 2*2*384;
    compose_kernel<<<(compose_items + 255)/256, 256, 0, stream>>>(
        msgW, msgrW, Wih, Whh, msgb, msgrb, WB, c34);

    init_kernel<<<B_GRAPHS, 128, 0, stream>>>(h, ei, A, indeg, outdeg, pack);

    for (int l = 0; l < 2; l++) {
        const unsigned short* WBl = WB + (size_t)l*512*640;
        const float* c34l = c34 + l*768;
        const float* bihl = bih + l*384;
        const float* bhhl = bhh + l*384;
        for (long long r0 = 0; r0 < NN; r0 += grows) {
            long long rc = NN - r0; if (rc > grows) rc = grows;
            gemm_kernel<<<dim3((unsigned)(rc/128), 2), 512, 0, stream>>>(
                A, WBl, G, (int)r0);
            if (l == 0)
                gru_kernel<false><<<(unsigned)(rc/16), 128, 0, stream>>>(
                    G, (int)r0, A, indeg, outdeg, pack, c34l, bihl, bhhl, nullptr);
            else
                gru_kernel<true><<<(unsigned)(rc/16), 128, 0, stream>>>(
                    G, (int)r0, A, indeg, outdeg, pack, c34l, bihl, bhhl, hf);
        }
    }

    pool_kernel<<<NN/256, 256, 0, stream>>>(
        hf, gmW, gmb, gmiW, gmib, P1, P2, sgb);
    outgemm_kernel<<<B_GRAPHS/32, 256, 0, stream>>>(
        P1, P2, sgb, fmW, fmb, fmiW, fmib, out1, out2);
}

// Round 4
// 450.968 us; speedup vs baseline: 4.9266x; 1.2591x over previous
//
#include <hip/hip_runtime.h>
#include <math.h>
#include <stdint.h>

#define NDIM 128
#define B_GRAPHS 8192
#define IDX 16
#define EPG 32
#define NN (B_GRAPHS*IDX)      // 131072 nodes
#define NE (B_GRAPHS*EPG)      // 262144 edges

typedef short bf16x8 __attribute__((ext_vector_type(8)));
typedef float f32x4  __attribute__((ext_vector_type(4)));
typedef unsigned short u16x4 __attribute__((ext_vector_type(4)));

__device__ inline unsigned short f2bf(float x) {
    union { float f; unsigned u; } v; v.f = x;
    unsigned r = v.u + 0x7fff + ((v.u >> 16) & 1);
    return (unsigned short)(r >> 16);
}
__device__ inline float bf2f(unsigned short b) {
    union { unsigned u; float f; } v; v.u = ((unsigned)b) << 16;
    return v.f;
}
__device__ inline float sigm(float x) { return 1.f/(1.f + __expf(-x)); }
__device__ inline float tanh_f(float x) {
    float ax = fabsf(x);
    float t  = __expf(-2.f*ax);
    float r  = (1.f - t)/(1.f + t);
    return copysignf(r, x);
}

#define GLOAD_LDS16(g, l) \
    __builtin_amdgcn_global_load_lds( \
        (const __attribute__((address_space(1))) unsigned int*)(g), \
        (__attribute__((address_space(3))) unsigned int*)(l), 16, 0, 0)

// ---------------------------------------------------------------------------
// Compose bf16 weight matrix WB[l][c][k]  (512 cols x 640 K) and c34.
// K segments: [S_in(128) | S_out(128) | indeg*h(128) | outdeg*h(128) | h(128)]
// Col segments: [r-sum(128) | z-sum(128) | gi_n(128) | gh_n(128)]
// ---------------------------------------------------------------------------
__global__ __launch_bounds__(256) void compose_kernel(
    const float* __restrict__ msg_W, const float* __restrict__ msgr_W,
    const float* __restrict__ Wih,   const float* __restrict__ Whh,
    const float* __restrict__ msg_b, const float* __restrict__ msgr_b,
    unsigned short* __restrict__ WB, float* __restrict__ c34)
{
    int idx = blockIdx.x*256 + threadIdx.x;
    const int TWB = 2*512*640;
    if (idx < TWB) {
        int l = idx / (512*640); int rem = idx - l*(512*640);
        int c = rem / 640; int k = rem - c*640;
        float val;
        if (k < 512) {
            if (c < 384) {
                const float* wih = Wih + l*384*256 + c*256;
                const float* M; int sc;
                if (k < 128)      { M = msg_W  + l*256*256; sc = k;       }
                else if (k < 256) { M = msgr_W + l*256*256; sc = k - 128; }
                else if (k < 384) { M = msg_W  + l*256*256; sc = k - 128; }
                else              { M = msgr_W + l*256*256; sc = k - 256; }
                float acc = 0.f;
                for (int q = 0; q < 256; q++) acc = fmaf(wih[q], M[q*256 + sc], acc);
                val = acc;
            } else val = 0.f;
        } else {
            int kk = k - 512;
            if (c < 256)      val = Whh[l*384*128 + c*128 + kk];
            else if (c < 384) val = 0.f;
            else              val = Whh[l*384*128 + (c-128)*128 + kk];
        }
        WB[idx] = f2bf(val);
    } else if (idx < TWB + 2*2*384) {
        int i2 = idx - TWB;
        int l = i2 / 768; int rem = i2 - l*768;
        int which = rem / 384; int r = rem - which*384;
        const float* wih = Wih + l*384*256 + r*256;
        const float* bb  = (which ? msgr_b : msg_b) + l*256;
        float acc = 0.f;
        for (int q = 0; q < 256; q++) acc = fmaf(wih[q], bb[q], acc);
        c34[l*768 + which*384 + r] = acc;
    }
}

// ---------------------------------------------------------------------------
// Init: per-graph edge decode + degree + packed edges + A0 build (bf16).
// A[v] = [S_in | S_out | indeg*h | outdeg*h | h]
// ---------------------------------------------------------------------------
__global__ __launch_bounds__(128) void init_kernel(
    const float* __restrict__ hin, const int* __restrict__ ei,
    unsigned short* __restrict__ A, float* __restrict__ indeg,
    float* __restrict__ outdeg, unsigned char* __restrict__ pack)
{
    int g = blockIdx.x, t = threadIdx.x;
    __shared__ float hb[16][128];
    __shared__ float sin_[16][128];
    __shared__ float sout_[16][128];
    __shared__ int sl[32], dl[32];
    __shared__ int cin[16], cout[16];
    __shared__ int flag64;
    int base = g*IDX;
    for (int r = 0; r < 16; r++) hb[r][t] = hin[(size_t)(base+r)*128 + t];
    for (int r = 0; r < 16; r++) { sin_[r][t] = 0.f; sout_[r][t] = 0.f; }
    if (t < 16) { cin[t] = 0; cout[t] = 0; }
    if (t == 0) {
        int orv = 0;
        for (int i = 1; i < 64; i += 2) orv |= ei[i];
        flag64 = (orv == 0);
    }
    __syncthreads();
    if (t < 32) {
        int e = g*EPG + t;
        int sv, dv;
        if (flag64) { sv = ei[2*e]; dv = ei[2*(NE + e)]; }
        else        { sv = ei[e];   dv = ei[NE + e];     }
        sl[t] = sv - base; dl[t] = dv - base;
        atomicAdd(&cout[sl[t]], 1); atomicAdd(&cin[dl[t]], 1);
        pack[g*32 + t] = (unsigned char)((sl[t] & 15) | ((dl[t] & 15) << 4));
    }
    __syncthreads();
    for (int e = 0; e < 32; e++) {
        sin_[dl[e]][t]  += hb[sl[e]][t];
        sout_[sl[e]][t] += hb[dl[e]][t];
    }
    for (int r = 0; r < 16; r++) {
        size_t v = base + r;
        float di = (float)cin[r], dof = (float)cout[r];
        A[v*640 + t]        = f2bf(sin_[r][t]);
        A[v*640 + 128 + t]  = f2bf(sout_[r][t]);
        A[v*640 + 256 + t]  = f2bf(di  * hb[r][t]);
        A[v*640 + 384 + t]  = f2bf(dof * hb[r][t]);
        A[v*640 + 512 + t]  = f2bf(hb[r][t]);
    }
    if (t < 16) { indeg[base+t] = (float)cin[t]; outdeg[base+t] = (float)cout[t]; }
}

// ---------------------------------------------------------------------------
// Fused MFMA GEMM + GRU + next-layer scatter. One block = 128 rows
// (8 complete graphs) x all 512 cols. 8 waves, each owns a 64-col stripe.
// K_STEP=32, 3-deep prefetch with counted vmcnt(5) (5 gload_lds/thread/stage).
// Epilogue: acc -> swizzled col-major LDS staging -> GRU in regs -> scatter
// via per-thread-owned LDS sin/sout -> A rewritten in place (block-local).
// LDS = 160 KiB exactly, 1 block/CU.
// ---------------------------------------------------------------------------
struct LoopBufs { unsigned short As[3][4096]; unsigned short Bs[3][16384]; };
union UnionRegion {
    LoopBufs lp;                 // 120 KB
    unsigned short Gs[512*128];  // 128 KB, col-major [col][row], swizzled
    float sio[2][128][128];      // 128 KB, [sin/sout][row][c]
};
struct SmemT { UnionRegion u; unsigned short hnewB[128][128]; };  // +32 KB

__device__ __forceinline__ void stage_tile(
    const unsigned short* __restrict__ A, const unsigned short* __restrict__ WB,
    int n0, int kc, unsigned short* As, unsigned short* Bs, int tid)
{
    {   // A tile 128x32: 512 units of 16B, linear in tid (gload_lds rule)
        int row = tid >> 2, s = tid & 3;
        int slot = s ^ ((row >> 2) & 3);   // pre-swizzled source
        GLOAD_LDS16(A + (size_t)(n0 + row)*640 + kc + slot*8, As + row*32 + s*8);
    }
#pragma unroll
    for (int i = 0; i < 4; i++) {          // B tile 512x32
        int u = i*512 + tid; int col = u >> 2, s = u & 3;
        int slot = s ^ ((col >> 2) & 3);
        GLOAD_LDS16(WB + (size_t)col*640 + kc + slot*8, Bs + col*32 + s*8);
    }
}

template <bool FINAL>
__global__ __launch_bounds__(512, 2) void fused_kernel(
    unsigned short* __restrict__ A,
    const unsigned short* __restrict__ WB,
    const float* __restrict__ indeg, const float* __restrict__ outdeg,
    const unsigned char* __restrict__ pack,
    const float* __restrict__ c34l,
    const float* __restrict__ bihl, const float* __restrict__ bhhl,
    float* __restrict__ hf)
{
    __shared__ SmemT sm;
    const int n0  = blockIdx.x * 128;
    const int tid = threadIdx.x;
    const int lane = tid & 63;
    const int wc  = tid >> 6;               // wave 0..7 -> col block wc*64
    const int l15 = lane & 15, l4 = lane >> 4;

    int ks_lo = 0, ks_hi = 20;
    if (wc == 4 || wc == 5) ks_hi = 16;     // cols 256-383: K < 512 only
    if (wc >= 6)            ks_lo = 16;     // cols 384-511: K >= 512 only

    f32x4 acc[8][4] = {};

    stage_tile(A, WB, n0, 0,  sm.u.lp.As[0], sm.u.lp.Bs[0], tid);
    stage_tile(A, WB, n0, 32, sm.u.lp.As[1], sm.u.lp.Bs[1], tid);
    asm volatile("s_waitcnt vmcnt(5)\n\ts_barrier" ::: "memory");

    for (int ks = 0; ks < 20; ks++) {
        int buf = ks % 3;
        if (ks + 2 < 20) {
            int nb = (ks + 2) % 3;
            stage_tile(A, WB, n0, (ks+2)*32, sm.u.lp.As[nb], sm.u.lp.Bs[nb], tid);
        }
        if (ks >= ks_lo && ks < ks_hi) {
            bf16x8 af[8], bfv[4];
            int slot = l4 ^ ((l15 >> 2) & 3);
            const unsigned short* Asb = sm.u.lp.As[buf];
            const unsigned short* Bsb = sm.u.lp.Bs[buf];
#pragma unroll
            for (int mi = 0; mi < 8; mi++)
                af[mi] = *(const bf16x8*)(Asb + (mi*16 + l15)*32 + slot*8);
#pragma unroll
            for (int ni = 0; ni < 4; ni++)
                bfv[ni] = *(const bf16x8*)(Bsb + (wc*64 + ni*16 + l15)*32 + slot*8);
#pragma unroll
            for (int mi = 0; mi < 8; mi++)
#pragma unroll
                for (int ni = 0; ni < 4; ni++)
                    acc[mi][ni] = __builtin_amdgcn_mfma_f32_16x16x32_bf16(
                        af[mi], bfv[ni], acc[mi][ni], 0, 0, 0);
        }
        if (ks + 2 < 20)
            asm volatile("s_waitcnt vmcnt(5)\n\ts_barrier" ::: "memory");
        else
            asm volatile("s_waitcnt vmcnt(0)\n\ts_barrier" ::: "memory");
    }

    // ---- stage acc -> Gs (col-major [col][128 rows], 16B-slot swizzle) ----
#pragma unroll
    for (int mi = 0; mi < 8; mi++) {
        int row0  = mi*16 + l4*4;
        int slotA = row0 >> 3;
        int half  = (row0 >> 2) & 1;
#pragma unroll
        for (int ni = 0; ni < 4; ni++) {
            int col = wc*64 + ni*16 + l15;
            int slot2 = slotA ^ (col & 15);
            u16x4 w;
            w[0] = f2bf(acc[mi][ni][0]); w[1] = f2bf(acc[mi][ni][1]);
            w[2] = f2bf(acc[mi][ni][2]); w[3] = f2bf(acc[mi][ni][3]);
            *(u16x4*)((char*)sm.u.Gs + col*256 + slot2*16 + half*8) = w;
        }
    }
    __syncthreads();

    // ---- phase 1: GRU per (channel, 2 graphs) thread ----
    const int c = tid & 127;
    const int q = tid >> 7;                 // 0..3 -> graphs 2q, 2q+1
    float c3r = c34l[c],     c3z = c34l[128+c], c3n = c34l[256+c];
    float c4r = c34l[384+c], c4z = c34l[512+c], c4n = c34l[640+c];
    float br   = bihl[c]     + bhhl[c];
    float bz   = bihl[128+c] + bhhl[128+c];
    float bin_ = bihl[256+c];
    float bhn  = bhhl[256+c];

    float hnew[2][16];
#pragma unroll
    for (int i = 0; i < 2; i++) {
        int gl = q*2 + i, r0 = gl*16;
#pragma unroll
        for (int rg = 0; rg < 4; rg++) {
            int row0 = r0 + rg*4;
            u16x4 sv[4];
#pragma unroll
            for (int seg = 0; seg < 4; seg++) {
                int col = seg*128 + c;
                int slot2 = (row0 >> 3) ^ (col & 15);
                sv[seg] = *(const u16x4*)((const char*)sm.u.Gs
                            + col*256 + slot2*16 + ((row0 >> 2) & 1)*8);
            }
#pragma unroll
            for (int j = 0; j < 4; j++) {
                int row = row0 + j; size_t v = (size_t)n0 + row;
                float di = indeg[v], dof = outdeg[v];
                float Gr  = bf2f(sv[0][j]), Gz  = bf2f(sv[1][j]);
                float Gin = bf2f(sv[2][j]), Ghn = bf2f(sv[3][j]);
                float hold = bf2f(A[v*640 + 512 + c]);
                float rr = sigm(Gr + di*c3r + dof*c4r + br);
                float zz = sigm(Gz + di*c3z + dof*c4z + bz);
                float nn = tanh_f(Gin + di*c3n + dof*c4n + bin_ + rr*(Ghn + bhn));
                float hv = nn + zz*(hold - nn);
                if (FINAL) hf[v*128 + c] = hv;
                else { hnew[i][rg*4 + j] = hv; sm.hnewB[row][c] = f2bf(hv); }
            }
        }
    }

    if (!FINAL) {
        __syncthreads();   // sio aliases Gs: all Gs reads must be done
        // ---- phase 2: scatter (per-thread-owned rows, wave-uniform edges) ----
#pragma unroll
        for (int i = 0; i < 2; i++) {
            int gl = q*2 + i, r0 = gl*16;
#pragma unroll
            for (int d = 0; d < 16; d++) {
                sm.u.sio[0][r0 + d][c] = 0.f;
                sm.u.sio[1][r0 + d][c] = 0.f;
            }
            size_t g = (size_t)(n0 >> 4) + gl;
            const unsigned int* pk = (const unsigned int*)(pack + g*32);
#pragma unroll
            for (int j = 0; j < 8; j++) {
                unsigned int u4 = pk[j];
#pragma unroll
                for (int b = 0; b < 4; b++) {
                    int p = (u4 >> (b*8)) & 255;
                    int s = p & 15, d = p >> 4;
                    sm.u.sio[0][r0 + d][c] += bf2f(sm.hnewB[r0 + s][c]);
                    sm.u.sio[1][r0 + s][c] += bf2f(sm.hnewB[r0 + d][c]);
                }
            }
#pragma unroll
            for (int d = 0; d < 16; d++) {
                int row = r0 + d; size_t v = (size_t)n0 + row;
                float di = indeg[v], dof = outdeg[v];
                float hv = hnew[i][d];
                A[v*640 + c]       = f2bf(sm.u.sio[0][row][c]);
                A[v*640 + 128 + c] = f2bf(sm.u.sio[1][row][c]);
                A[v*640 + 256 + c] = f2bf(di  * hv);
                A[v*640 + 384 + c] = f2bf(dof * hv);
                A[v*640 + 512 + c] = f2bf(hv);
            }
        }
    }
}

// ---------------------------------------------------------------------------
// Pool: per-node gates (all threads active, float4 dots) + gated sums.
// ---------------------------------------------------------------------------
__global__ __launch_bounds__(256) void pool_kernel(
    const float* __restrict__ hf,
    const float* __restrict__ gm_W,  const float* __restrict__ gm_b,
    const float* __restrict__ gmi_W, const float* __restrict__ gmi_b,
    float* __restrict__ P1, float* __restrict__ P2, float* __restrict__ sg)
{
    const int t = threadIdx.x;
    const int nbase = blockIdx.x * 256;
    __shared__ float g1s[256], g2s[256];

    {
        const float4* hp = (const float4*)(hf + (size_t)(nbase + t)*128);
        float a1 = 0.f, a2 = 0.f;
#pragma unroll
        for (int k = 0; k < 32; k++) {
            float4 hv = hp[k];
            float4 w1 = ((const float4*)gm_W)[k];
            float4 w2 = ((const float4*)gmi_W)[k];
            a1 = fmaf(hv.x,w1.x,fmaf(hv.y,w1.y,fmaf(hv.z,w1.z,fmaf(hv.w,w1.w,a1))));
            a2 = fmaf(hv.x,w2.x,fmaf(hv.y,w2.y,fmaf(hv.z,w2.z,fmaf(hv.w,w2.w,a2))));
        }
        g1s[t] = sigm(a1 + gm_b[0]);
        g2s[t] = sigm(a2 + gmi_b[0]);
    }
    __syncthreads();

    int c  = t & 127;
    int gh = t >> 7;
#pragma unroll
    for (int i = 0; i < 8; i++) {
        int glc = gh*8 + i;
        float p1 = 0.f, p2 = 0.f;
#pragma unroll
        for (int r = 0; r < 16; r++) {
            float x = hf[(size_t)(nbase + glc*16 + r)*128 + c];
            p1 = fmaf(g1s[glc*16+r], x, p1);
            p2 = fmaf(g2s[glc*16+r], x, p2);
        }
        size_t g = nbase/16 + glc;
        P1[g*128 + c] = p1;
        P2[g*128 + c] = p2;
    }
    if (t < 32) {
        int glc = t >> 1, which = t & 1;
        const float* gs = which ? g2s : g1s;
        float s = 0.f;
        for (int r = 0; r < 16; r++) s += gs[glc*16+r];
        sg[(nbase/16 + glc)*2 + which] = s;
    }
}

// ---------------------------------------------------------------------------
// Out projection: out[g][c] = fm_W[c].P[g] + fm_b[c]*sg[g].
// ---------------------------------------------------------------------------
__global__ __launch_bounds__(256) void outgemm_kernel(
    const float* __restrict__ P1, const float* __restrict__ P2,
    const float* __restrict__ sg,
    const float* __restrict__ fm_W,  const float* __restrict__ fm_b,
    const float* __restrict__ fmi_W, const float* __restrict__ fmi_b,
    float* __restrict__ out1, float* __restrict__ out2)
{
    const int g0 = blockIdx.x * 32;
    const int t  = threadIdx.x;
    __shared__ float Ws[128][33];
    __shared__ float Ps[32][33];
    const int tc = t & 15, tg = t >> 4;

    for (int pass = 0; pass < 2; pass++) {
        const float* P  = pass ? P2 : P1;
        const float* W  = pass ? fmi_W : fm_W;
        const float* bb = pass ? fmi_b : fm_b;
        float acc[2][8] = {};
        for (int kc = 0; kc < 128; kc += 32) {
#pragma unroll
            for (int i = 0; i < 16; i++) {
                int u = i*256 + t; int r = u >> 5, k = u & 31;
                Ws[r][k] = W[(size_t)r*128 + kc + k];
            }
#pragma unroll
            for (int i = 0; i < 4; i++) {
                int u = i*256 + t; int r = u >> 5, k = u & 31;
                Ps[r][k] = P[(size_t)(g0 + r)*128 + kc + k];
            }
            __syncthreads();
#pragma unroll 8
            for (int k = 0; k < 32; k++) {
                float p0 = Ps[tg*2][k], p1v = Ps[tg*2+1][k];
#pragma unroll
                for (int j = 0; j < 8; j++) {
                    float w = Ws[tc*8+j][k];
                    acc[0][j] = fmaf(p0,  w, acc[0][j]);
                    acc[1][j] = fmaf(p1v, w, acc[1][j]);
                }
            }
            __syncthreads();
        }
        float* outp = pass ? out2 : out1;
#pragma unroll
        for (int i = 0; i < 2; i++) {
            int g = g0 + tg*2 + i;
            float sgv = sg[g*2 + pass];
#pragma unroll
            for (int j = 0; j < 8; j++) {
                int cc = tc*8 + j;
                outp[(size_t)g*128 + cc] = acc[i][j] + bb[cc]*sgv;
            }
        }
    }
}

// ---------------------------------------------------------------------------
extern "C" void kernel_launch(void* const* d_in, const int* in_sizes, int n_in,
                              void* d_out, int out_size, void* d_ws, size_t ws_size,
                              hipStream_t stream)
{
    const float* h     = (const float*)d_in[0];
    const int*   ei    = (const int*)d_in[1];
    const float* msgW  = (const float*)d_in[2];
    const float* msgb  = (const float*)d_in[3];
    const float* msgrW = (const float*)d_in[4];
    const float* msgrb = (const float*)d_in[5];
    const float* Wih   = (const float*)d_in[6];
    const float* Whh   = (const float*)d_in[7];
    const float* bih   = (const float*)d_in[8];
    const float* bhh   = (const float*)d_in[9];
    const float* fmW   = (const float*)d_in[10];
    const float* fmb   = (const float*)d_in[11];
    const float* gmW   = (const float*)d_in[12];
    const float* gmb   = (const float*)d_in[13];
    const float* fmiW  = (const float*)d_in[14];
    const float* fmib  = (const float*)d_in[15];
    const float* gmiW  = (const float*)d_in[16];
    const float* gmib  = (const float*)d_in[17];

    char* w = (char*)d_ws;
    unsigned short* A    = (unsigned short*)w;  w += (size_t)NN*640*2;     // 167.8 MB
    unsigned short* WB   = (unsigned short*)w;  w += (size_t)2*512*640*2;  // 1.3 MB
    float* c34   = (float*)w;                   w += (size_t)2*768*4;
    float* indeg = (float*)w;                   w += (size_t)NN*4;
    float* outdeg= (float*)w;                   w += (size_t)NN*4;
    unsigned char* pack = (unsigned char*)w;    w += (size_t)B_GRAPHS*32;
    float* P1    = (float*)w;                   w += (size_t)B_GRAPHS*128*4;
    float* P2    = (float*)w;                   w += (size_t)B_GRAPHS*128*4;
    float* sgb   = (float*)w;                   w += (size_t)B_GRAPHS*2*4;

    float* hf   = (float*)d_out;
    float* out1 = hf + (size_t)NN*128;
    float* out2 = out1 + (size_t)B_GRAPHS*128;

    int compose_items = 2*512*640 + 2*2*384;
    compose_kernel<<<(compose_items + 255)/256, 256, 0, stream>>>(
        msgW, msgrW, Wih, Whh, msgb, msgrb, WB, c34);

    init_kernel<<<B_GRAPHS, 128, 0, stream>>>(h, ei, A, indeg, outdeg, pack);

    fused_kernel<false><<<NN/128, 512, 0, stream>>>(
        A, WB, indeg, outdeg, pack, c34, bih, bhh, nullptr);
    fused_kernel<true><<<NN/128, 512, 0, stream>>>(
        A, WB + (size_t)512*640, indeg, outdeg, pack,
        c34 + 768, bih + 384, bhh + 384, hf);

    pool_kernel<<<NN/256, 256, 0, stream>>>(
        hf, gmW, gmb, gmiW, gmib, P1, P2, sgb);
    outgemm_kernel<<<B_GRAPHS/32, 256, 0, stream>>>(
        P1, P2, sgb, fmW, fmb, fmiW, fmib, out1, out2);
}